// Round 9
// baseline (548.067 us; speedup 1.0000x reference)
//
#include <hip/hip_runtime.h>

using u16 = unsigned short;
using u32 = unsigned int;
using u64 = unsigned long long;
typedef short short8 __attribute__((ext_vector_type(8)));
typedef unsigned short ushort8 __attribute__((ext_vector_type(8)));
typedef float f32x4 __attribute__((ext_vector_type(4)));

#define GB  16
#define GNV 8192
#define GNC 4096
#define GD  128
#define GE  49152

#define MFMA __builtin_amdgcn_mfma_f32_16x16x32_bf16

// ---------- helpers ----------

__device__ __forceinline__ u16 f2bf(float f){
    u32 u = __builtin_bit_cast(u32, f);
    u32 r = (u >> 16) & 1u;
    u += 0x7fffu + r;            // round-to-nearest-even
    return (u16)(u >> 16);
}

__device__ __forceinline__ float bf2f(u16 x){
    return __builtin_bit_cast(float, (u32)x << 16);
}

__device__ __forceinline__ u32 cvtpk(float lo, float hi){
    u32 r;
    asm("v_cvt_pk_bf16_f32 %0, %1, %2" : "=v"(r) : "v"(lo), "v"(hi));
    return r;
}

__device__ __forceinline__ ushort8 pack8(float4 v0, float4 v1){
    union { u32 u[4]; ushort8 v; } q;
    q.u[0] = cvtpk(v0.x, v0.y); q.u[1] = cvtpk(v0.z, v0.w);
    q.u[2] = cvtpk(v1.x, v1.y); q.u[3] = cvtpk(v1.z, v1.w);
    return q.v;
}

__device__ __forceinline__ u64 pack4(float a, float b, float c, float d){
    return (u64)cvtpk(a, b) | ((u64)cvtpk(c, d) << 32);
}

__device__ __forceinline__ float sigmoidf_(float x){
    return __fdividef(1.f, 1.f + __expf(-x));
}

__device__ __forceinline__ float tanhf_fast(float x){
    float xc = fminf(15.f, fmaxf(-15.f, x));
    float t  = __expf(2.f * xc);
    return __fdividef(t - 1.f, t + 1.f);
}

// LDS tiles [16 rows][256B], XOR-swizzled (G4 fix for D=128 column reads).
__device__ __forceinline__ char* swzp(const void* base, int row, int bc){
    return (char*)base + row * 256 + (bc ^ ((row & 7) << 4));
}

// A-fragment for mfma_f32_16x16x32_bf16 from a swizzled LDS tile:
// lane&15 = row, k = (lane>>4)*8 + e.
__device__ __forceinline__ short8 ldfrag(const u16* tile, int row, int lane, int ks){
    int bc = ks * 64 + ((lane >> 4) << 4);
    return *(const short8*)swzp(tile, row, bc);
}

// ---------- CSR build ----------

__global__ void k_hist(const int* __restrict__ ec, const int* __restrict__ ev,
                       int* cc, int* cv){
    int e = blockIdx.x * 256 + threadIdx.x;
    if (e < GE){ atomicAdd(&cc[ec[e]], 1); atomicAdd(&cv[ev[e]], 1); }
}

__global__ __launch_bounds__(1024) void k_scan2(const int* __restrict__ cnt_c, int* off_c, int* cur_c,
                                                const int* __restrict__ cnt_v, int* off_v, int* cur_v){
    const int* cnt = blockIdx.x ? cnt_v : cnt_c;
    int* off = blockIdx.x ? off_v : off_c;
    int* cur = blockIdx.x ? cur_v : cur_c;
    const int n = blockIdx.x ? GNV : GNC;
    __shared__ int part[1024];
    int tid = threadIdx.x;
    int chunk = n >> 10;
    int base = tid * chunk;
    int s = 0;
    for (int i = 0; i < chunk; ++i) s += cnt[base + i];
    part[tid] = s;
    __syncthreads();
    #pragma unroll
    for (int ofs = 1; ofs < 1024; ofs <<= 1){
        int v = (tid >= ofs) ? part[tid - ofs] : 0;
        __syncthreads();
        part[tid] += v;
        __syncthreads();
    }
    if (tid == 1023) off[n] = part[1023];
    int run = part[tid] - s;
    for (int i = 0; i < chunk; ++i){
        off[base + i] = run; cur[base + i] = run; run += cnt[base + i];
    }
}

__global__ void k_fill(const int* __restrict__ ec, const int* __restrict__ ev,
                       int* cur_c, int* lst_c, int* cur_v, int* lst_v){
    int e = blockIdx.x * 256 + threadIdx.x;
    if (e < GE){
        int c = ec[e], v = ev[e];
        lst_c[atomicAdd(&cur_c[c], 1)] = v;
        lst_v[atomicAdd(&cur_v[v], 1)] = c;
    }
}

__global__ void k_sort2(const int* __restrict__ off_c, int* lst_c,
                        const int* __restrict__ off_v, int* lst_v){
    int i = blockIdx.x * 256 + threadIdx.x;
    const int* off; int* lst; int idx;
    if (i < GNC){ off = off_c; lst = lst_c; idx = i; }
    else if (i < GNC + GNV){ off = off_v; lst = lst_v; idx = i - GNC; }
    else return;
    int s = off[idx], e = off[idx + 1];
    for (int a = s + 1; a < e; ++a){
        int v = lst[a]; int b = a - 1;
        while (b >= s && lst[b] > v){ lst[b + 1] = lst[b]; --b; }
        lst[b + 1] = v;
    }
}

__global__ void k_cvt6(const float* __restrict__ s0, const float* __restrict__ s1,
                       const float* __restrict__ s2, const float* __restrict__ s3,
                       const float* __restrict__ s4, const float* __restrict__ s5,
                       u16* __restrict__ dst){
    int i = blockIdx.x * 256 + threadIdx.x;      // total 229376
    const float* s; int off;
    if (i < 16384)       { s = s0; off = i; }
    else if (i < 32768)  { s = s1; off = i - 16384; }
    else if (i < 81920)  { s = s2; off = i - 32768; }
    else if (i < 131072) { s = s3; off = i - 81920; }
    else if (i < 180224) { s = s4; off = i - 131072; }
    else                 { s = s5; off = i - 180224; }
    dst[i] = f2bf(s[off]);
}

// ---------- transpose (B,N,D) f32 -> node-major (N,B,D) bf16 ----------
// One block per node (v nodes then c nodes). Thread t: b=t>>4, d0=(t&15)*8.

__global__ __launch_bounds__(256) void k_trn(const float* __restrict__ vfe,
                                             const float* __restrict__ cfe,
                                             u16* __restrict__ vT, u16* __restrict__ cfT){
    const int t = threadIdx.x;
    const int b = t >> 4, d0 = (t & 15) * 8;
    int node = blockIdx.x;
    const float* src; u16* dst; int n;
    if (node < GNV){ src = vfe; dst = vT; n = GNV; }
    else { node -= GNV; src = cfe; dst = cfT; n = GNC; }
    const float4* s = (const float4*)(src + ((size_t)b * n + node) * GD + d0);
    *(ushort8*)(dst + ((size_t)node << 11) + b * 128 + d0) = pack8(s[0], s[1]);
}

// ---------- fused spmm + msg-net + GRU (one 16-row group per block-iter) ----------
// Block 512 thr = 8 waves. Phase0: gather X from srcT + stage H from HT into
// LDS (32 thr/node, 256B contiguous chunks). Phase1/2: msg GEMM1+gelu+GEMM2
// via LDS (per-wave 16 cols, W1/W2 frags in regs). Phase3: GRU (6 gate-slice
// weight frags in regs), f32 out + optional bf16 node-major OutT via LDS.

__global__ __launch_bounds__(512) void k_fused(
    const u16* __restrict__ srcT, const int* __restrict__ off, const int* __restrict__ lst,
    const u16* __restrict__ HT,
    const u16* __restrict__ W1, const float* __restrict__ b1,
    const u16* __restrict__ W2, const float* __restrict__ b2,
    const u16* __restrict__ Wih, const float* __restrict__ bih,
    const u16* __restrict__ Whh, const float* __restrict__ bhh,
    float* __restrict__ Out, u16* __restrict__ OutT,
    int logN, int ngroups)
{
    __shared__ __align__(16) u16 Xs[16 * 128];   // 4KB each
    __shared__ __align__(16) u16 Hs[16 * 128];
    __shared__ __align__(16) u16 Gs[16 * 128];
    __shared__ __align__(16) u16 Ms[16 * 128];
    __shared__ __align__(16) u16 Os[16 * 128];
    const int tid = threadIdx.x, lane = tid & 63, w = tid >> 6;
    const int l15 = lane & 15, rg = lane >> 4;
    const int j = w * 16 + l15;            // this lane's output column

    // persistent register weights
    short8 w1f[4], w2f[4], wf[6][4];
    #pragma unroll
    for (int ks = 0; ks < 4; ++ks){
        w1f[ks] = *(const short8*)(W1 + (size_t)j * 128 + ks * 32 + rg * 8);
        w2f[ks] = *(const short8*)(W2 + (size_t)j * 128 + ks * 32 + rg * 8);
    }
    #pragma unroll
    for (int g = 0; g < 3; ++g){
        #pragma unroll
        for (int ks = 0; ks < 4; ++ks){
            wf[g][ks]     = *(const short8*)(Wih + (size_t)(g * 128 + j) * 128 + ks * 32 + rg * 8);
            wf[g + 3][ks] = *(const short8*)(Whh + (size_t)(g * 128 + j) * 128 + ks * 32 + rg * 8);
        }
    }
    const float bb1 = b1[j], bb2 = b2[j];
    const float bir = bih[j]       + bhh[j];
    const float biz = bih[128 + j] + bhh[128 + j];
    const float bin = bih[256 + j];
    const float bhn = bhh[256 + j];

    // gather-phase assignment: 32 threads per row
    const int grow = tid >> 5;             // row in group (node index low bits)
    const int q    = tid & 31;
    const int d0   = q * 4;                // 4 u16 = 8B per thread
    const int gpb_shift = logN - 4;        // groups per batch = N/16

    for (int g = blockIdx.x; g < ngroups; g += gridDim.x){
        const int b = g >> gpb_shift;
        const int node0 = (g & ((1 << gpb_shift) - 1)) << 4;
        const int mynode = node0 + grow;

        // ---- phase 0: stage H, gather X ----
        {
            u64 hv = *(const u64*)(HT + (((size_t)mynode) << 11) + b * 128 + d0);
            *(u64*)swzp(Hs, grow, q * 8) = hv;

            const int s = off[mynode], e = off[mynode + 1];
            const u16* base = srcT + b * 128 + d0;
            float a0[4] = {0,0,0,0}, a1[4] = {0,0,0,0};
            int a = s;
            for (; a + 2 <= e; a += 2){
                u64 v0 = *(const u64*)(base + ((size_t)lst[a]     << 11));
                u64 v1 = *(const u64*)(base + ((size_t)lst[a + 1] << 11));
                #pragma unroll
                for (int i = 0; i < 4; ++i){
                    a0[i] += bf2f((u16)(v0 >> (16 * i)));
                    a1[i] += bf2f((u16)(v1 >> (16 * i)));
                }
            }
            if (a < e){
                u64 v0 = *(const u64*)(base + ((size_t)lst[a] << 11));
                #pragma unroll
                for (int i = 0; i < 4; ++i) a0[i] += bf2f((u16)(v0 >> (16 * i)));
            }
            *(u64*)swzp(Xs, grow, q * 8) =
                pack4(a0[0] + a1[0], a0[1] + a1[1], a0[2] + a1[2], a0[3] + a1[3]);
        }
        __syncthreads();

        // ---- phase 1: GEMM1 + gelu -> Gs ----
        {
            f32x4 acc = {0, 0, 0, 0};
            #pragma unroll
            for (int ks = 0; ks < 4; ++ks)
                acc = MFMA(ldfrag(Xs, l15, lane, ks), w1f[ks], acc, 0, 0, 0);
            #pragma unroll
            for (int i = 0; i < 4; ++i){
                float v = acc[i] + bb1;
                float ge = 0.5f * v * (1.f + erff(v * 0.70710678f));   // exact gelu
                *(u16*)swzp(Gs, rg * 4 + i, j * 2) = f2bf(ge);
            }
        }
        __syncthreads();

        // ---- phase 2: GEMM2 -> Ms ----
        {
            f32x4 acc = {0, 0, 0, 0};
            #pragma unroll
            for (int ks = 0; ks < 4; ++ks)
                acc = MFMA(ldfrag(Gs, l15, lane, ks), w2f[ks], acc, 0, 0, 0);
            #pragma unroll
            for (int i = 0; i < 4; ++i)
                *(u16*)swzp(Ms, rg * 4 + i, j * 2) = f2bf(acc[i] + bb2);
        }
        __syncthreads();

        // ---- phase 3: GRU ----
        {
            f32x4 ar = {0,0,0,0}, az = {0,0,0,0}, an = {0,0,0,0}, hn = {0,0,0,0};
            #pragma unroll
            for (int ks = 0; ks < 4; ++ks){
                short8 x = ldfrag(Ms, l15, lane, ks);
                short8 h = ldfrag(Hs, l15, lane, ks);
                ar = MFMA(x, wf[0][ks], ar, 0, 0, 0);
                az = MFMA(x, wf[1][ks], az, 0, 0, 0);
                an = MFMA(x, wf[2][ks], an, 0, 0, 0);
                ar = MFMA(h, wf[3][ks], ar, 0, 0, 0);
                az = MFMA(h, wf[4][ks], az, 0, 0, 0);
                hn = MFMA(h, wf[5][ks], hn, 0, 0, 0);
            }
            #pragma unroll
            for (int i = 0; i < 4; ++i){
                int rl = rg * 4 + i;
                float h0 = bf2f(*(const u16*)swzp(Hs, rl, j * 2));
                float rr = sigmoidf_(ar[i] + bir);
                float zz = sigmoidf_(az[i] + biz);
                float nn = tanhf_fast(an[i] + bin + rr * (hn[i] + bhn));
                float val = (1.f - zz) * nn + zz * h0;
                Out[((size_t)g * 16 + rl) * GD + j] = val;
                if (OutT) *(u16*)swzp(Os, rl, j * 2) = f2bf(val);
            }
        }
        if (OutT){
            __syncthreads();
            u64 ov = *(const u64*)swzp(Os, grow, q * 8);
            *(u64*)(OutT + (((size_t)mynode) << 11) + b * 128 + d0) = ov;
        }
        __syncthreads();   // protect LDS reuse by next group
    }
}

// ---------- launch ----------

extern "C" void kernel_launch(void* const* d_in, const int* in_sizes, int n_in,
                              void* d_out, int out_size, void* d_ws, size_t ws_size,
                              hipStream_t stream){
    const float* v_feats  = (const float*)d_in[0];
    const float* c_feats  = (const float*)d_in[1];
    const int*   edge_chk = (const int*)d_in[2];
    const int*   edge_var = (const int*)d_in[3];
    const float* msg_w1   = (const float*)d_in[4];
    const float* msg_b1   = (const float*)d_in[5];
    const float* msg_w2   = (const float*)d_in[6];
    const float* msg_b2   = (const float*)d_in[7];
    const float* var_w_ih = (const float*)d_in[8];
    const float* var_w_hh = (const float*)d_in[9];
    const float* var_b_ih = (const float*)d_in[10];
    const float* var_b_hh = (const float*)d_in[11];
    const float* chk_w_ih = (const float*)d_in[12];
    const float* chk_w_hh = (const float*)d_in[13];
    const float* chk_b_ih = (const float*)d_in[14];
    const float* chk_b_hh = (const float*)d_in[15];

    float* out_v = (float*)d_out;
    float* out_c = out_v + (size_t)GB * GNV * GD;

    char* p = (char*)d_ws;
    auto take = [&](size_t bytes) -> void* {
        void* r = (void*)p; p += (bytes + 255) & ~(size_t)255; return r;
    };
    int* cnt_c = (int*)take(GNC * 4);
    int* cnt_v = (int*)take(GNV * 4);
    int* off_c = (int*)take((GNC + 1) * 4);
    int* off_v = (int*)take((GNV + 1) * 4);
    int* cur_c = (int*)take(GNC * 4);
    int* cur_v = (int*)take(GNV * 4);
    int* lst_c = (int*)take(GE * 4);
    int* lst_v = (int*)take(GE * 4);
    u16* w1b  = (u16*)take((size_t)GD * GD * 2);       // contiguous bf16 weights
    u16* w2b  = (u16*)take((size_t)GD * GD * 2);
    u16* cihb = (u16*)take((size_t)3 * GD * GD * 2);
    u16* chhb = (u16*)take((size_t)3 * GD * GD * 2);
    u16* vihb = (u16*)take((size_t)3 * GD * GD * 2);
    u16* vhhb = (u16*)take((size_t)3 * GD * GD * 2);
    u16* vT  = (u16*)take((size_t)GNV * GB * GD * 2);  // (NV,B,D) bf16 v_feats
    u16* cfT = (u16*)take((size_t)GNC * GB * GD * 2);  // (NC,B,D) bf16 c_feats
    u16* cT  = (u16*)take((size_t)GNC * GB * GD * 2);  // (NC,B,D) bf16 c_new

    hipMemsetAsync(cnt_c, 0, (GNC + GNV) * 4, stream);
    k_hist<<<(GE + 255) / 256, 256, 0, stream>>>(edge_chk, edge_var, cnt_c, cnt_v);
    k_scan2<<<2, 1024, 0, stream>>>(cnt_c, off_c, cur_c, cnt_v, off_v, cur_v);
    k_fill<<<(GE + 255) / 256, 256, 0, stream>>>(edge_chk, edge_var, cur_c, lst_c, cur_v, lst_v);
    k_sort2<<<(GNC + GNV + 255) / 256, 256, 0, stream>>>(off_c, lst_c, off_v, lst_v);
    k_cvt6<<<896, 256, 0, stream>>>(msg_w1, msg_w2, chk_w_ih, chk_w_hh, var_w_ih, var_w_hh, w1b);
    k_trn<<<GNV + GNC, 256, 0, stream>>>(v_feats, c_feats, vT, cfT);

    // v -> c : gather vT, msg, GRU(h=c_feats) -> out_c (f32) + cT (bf16 node-major)
    k_fused<<<2048, 512, 0, stream>>>(vT, off_c, lst_c, cfT,
                                      w1b, msg_b1, w2b, msg_b2,
                                      cihb, chk_b_ih, chhb, chk_b_hh,
                                      out_c, cT, 12, (GB * GNC) / 16);
    // c -> v : gather cT, msg, GRU(h=v_feats) -> out_v (f32)
    k_fused<<<2048, 512, 0, stream>>>(cT, off_v, lst_v, vT,
                                      w1b, msg_b1, w2b, msg_b2,
                                      vihb, var_b_ih, vhhb, var_b_hh,
                                      out_v, (u16*)nullptr, 13, (GB * GNV) / 16);
}

// Round 10
// 352.281 us; speedup vs baseline: 1.5558x; 1.5558x over previous
//
#include <hip/hip_runtime.h>

using u16 = unsigned short;
using u32 = unsigned int;
using u64 = unsigned long long;
typedef short short8 __attribute__((ext_vector_type(8)));
typedef unsigned short ushort8 __attribute__((ext_vector_type(8)));
typedef float f32x4 __attribute__((ext_vector_type(4)));

#define GB  16
#define GNV 8192
#define GNC 4096
#define GD  128
#define GE  49152

#define MFMA __builtin_amdgcn_mfma_f32_16x16x32_bf16

// ---------- helpers ----------

__device__ __forceinline__ u16 f2bf(float f){
    u32 u = __builtin_bit_cast(u32, f);
    u32 r = (u >> 16) & 1u;
    u += 0x7fffu + r;            // round-to-nearest-even
    return (u16)(u >> 16);
}

__device__ __forceinline__ float bf2f(u16 x){
    return __builtin_bit_cast(float, (u32)x << 16);
}

__device__ __forceinline__ u32 cvtpk(float lo, float hi){
    u32 r;
    asm("v_cvt_pk_bf16_f32 %0, %1, %2" : "=v"(r) : "v"(lo), "v"(hi));
    return r;
}

__device__ __forceinline__ ushort8 pack8(float4 v0, float4 v1){
    union { u32 u[4]; ushort8 v; } q;
    q.u[0] = cvtpk(v0.x, v0.y); q.u[1] = cvtpk(v0.z, v0.w);
    q.u[2] = cvtpk(v1.x, v1.y); q.u[3] = cvtpk(v1.z, v1.w);
    return q.v;
}

__device__ __forceinline__ u64 pack4(float a, float b, float c, float d){
    return (u64)cvtpk(a, b) | ((u64)cvtpk(c, d) << 32);
}

__device__ __forceinline__ float sigmoidf_(float x){
    return __fdividef(1.f, 1.f + __expf(-x));
}

__device__ __forceinline__ float tanhf_fast(float x){
    float xc = fminf(15.f, fmaxf(-15.f, x));
    float t  = __expf(2.f * xc);
    return __fdividef(t - 1.f, t + 1.f);
}

// ---- MFMA-fragment-ordered global layout for A-operands ----
// Group g = r/16 owns a 4KB block; ks -> 1KB; lane l -> 16B of row (l&15),
// elements [ks*32 + (l>>4)*8, +8). u16 index of element (r, c):
__device__ __forceinline__ size_t fidx(int r, int c){
    return ((size_t)(r >> 4) << 11) + ((c >> 5) << 9)
         + (((r & 15) + (((c & 31) >> 3) << 4)) << 3) + (c & 7);
}

// LDS tiles [rows][256B], XOR-swizzled (G4 fix). Used by k_msg's Gs only.
__device__ __forceinline__ char* swzp(const void* base, int row, int bc){
    return (char*)base + row * 256 + (bc ^ ((row & 7) << 4));
}

__device__ __forceinline__ short8 ldfrag(const u16* tile, int row, int lane, int ks){
    int bc = ks * 64 + ((lane >> 4) << 4);
    return *(const short8*)swzp(tile, row, bc);
}

// ---------- CSR build ----------

__global__ void k_hist(const int* __restrict__ ec, const int* __restrict__ ev,
                       int* cc, int* cv){
    int e = blockIdx.x * 256 + threadIdx.x;
    if (e < GE){ atomicAdd(&cc[ec[e]], 1); atomicAdd(&cv[ev[e]], 1); }
}

__global__ __launch_bounds__(1024) void k_scan2(const int* __restrict__ cnt_c, int* off_c, int* cur_c,
                                                const int* __restrict__ cnt_v, int* off_v, int* cur_v){
    const int* cnt = blockIdx.x ? cnt_v : cnt_c;
    int* off = blockIdx.x ? off_v : off_c;
    int* cur = blockIdx.x ? cur_v : cur_c;
    const int n = blockIdx.x ? GNV : GNC;
    __shared__ int part[1024];
    int tid = threadIdx.x;
    int chunk = n >> 10;
    int base = tid * chunk;
    int s = 0;
    for (int i = 0; i < chunk; ++i) s += cnt[base + i];
    part[tid] = s;
    __syncthreads();
    #pragma unroll
    for (int ofs = 1; ofs < 1024; ofs <<= 1){
        int v = (tid >= ofs) ? part[tid - ofs] : 0;
        __syncthreads();
        part[tid] += v;
        __syncthreads();
    }
    if (tid == 1023) off[n] = part[1023];
    int run = part[tid] - s;
    for (int i = 0; i < chunk; ++i){
        off[base + i] = run; cur[base + i] = run; run += cnt[base + i];
    }
}

__global__ void k_fill(const int* __restrict__ ec, const int* __restrict__ ev,
                       int* cur_c, int* lst_c, int* cur_v, int* lst_v){
    int e = blockIdx.x * 256 + threadIdx.x;
    if (e < GE){
        int c = ec[e], v = ev[e];
        lst_c[atomicAdd(&cur_c[c], 1)] = v;
        lst_v[atomicAdd(&cur_v[v], 1)] = c;
    }
}

__global__ void k_sort2(const int* __restrict__ off_c, int* lst_c,
                        const int* __restrict__ off_v, int* lst_v){
    int i = blockIdx.x * 256 + threadIdx.x;
    const int* off; int* lst; int idx;
    if (i < GNC){ off = off_c; lst = lst_c; idx = i; }
    else if (i < GNC + GNV){ off = off_v; lst = lst_v; idx = i - GNC; }
    else return;
    int s = off[idx], e = off[idx + 1];
    for (int a = s + 1; a < e; ++a){
        int v = lst[a]; int b = a - 1;
        while (b >= s && lst[b] > v){ lst[b + 1] = lst[b]; --b; }
        lst[b + 1] = v;
    }
}

__global__ void k_cvt6(const float* __restrict__ s0, const float* __restrict__ s1,
                       const float* __restrict__ s2, const float* __restrict__ s3,
                       const float* __restrict__ s4, const float* __restrict__ s5,
                       u16* __restrict__ dst){
    int i = blockIdx.x * 256 + threadIdx.x;      // total 229376
    const float* s; int off;
    if (i < 16384)       { s = s0; off = i; }
    else if (i < 32768)  { s = s1; off = i - 16384; }
    else if (i < 81920)  { s = s2; off = i - 32768; }
    else if (i < 131072) { s = s3; off = i - 81920; }
    else if (i < 180224) { s = s4; off = i - 131072; }
    else                 { s = s5; off = i - 180224; }
    dst[i] = f2bf(s[off]);
}

// ---------- group-coalesced transpose: v_feats -> vT + vF, c_feats -> cF ----------
// One block per frag GROUP (16 consecutive nodes at fixed b). Thread t owns
// frag slot t*8 u16 (16B, fully contiguous across the block).

__global__ __launch_bounds__(256) void k_trg(const float* __restrict__ vfe,
                                             const float* __restrict__ cfe,
                                             u16* __restrict__ vT, u16* __restrict__ vF,
                                             u16* __restrict__ cF){
    const int t = threadIdx.x;
    const int ks = t >> 6, sub = (t >> 4) & 3, row = t & 15;
    const int c = ks * 32 + sub * 8;
    int gg = blockIdx.x;
    const float* src; u16* dstF; int n, b, node0, grp; u16* dstT = nullptr;
    if (gg < 8192){ b = gg >> 9; node0 = (gg & 511) << 4; grp = gg;
                    src = vfe; dstF = vF; n = GNV; dstT = vT; }
    else { int idx = gg - 8192; b = idx >> 8; node0 = (idx & 255) << 4; grp = idx;
           src = cfe; dstF = cF; n = GNC; }
    const float4* s = (const float4*)(src + ((size_t)b * n + node0 + row) * GD + c);
    float4 v0 = s[0], v1 = s[1];
    ushort8 pk = pack8(v0, v1);
    *(ushort8*)(dstF + ((size_t)grp << 11) + t * 8) = pk;
    if (dstT)
        *(ushort8*)(dstT + ((size_t)(node0 + row) << 11) + b * 128 + c) = pk;
}

// ---------- simple transpose: f32 (B,N,D) -> bf16 node-major (N,B,D) ----------

__global__ __launch_bounds__(256) void k_tr1(const float* __restrict__ src,
                                             u16* __restrict__ dst, int n){
    const int node = blockIdx.x, t = threadIdx.x;
    const int b = t >> 4, d0 = (t & 15) * 8;
    const float4* s = (const float4*)(src + ((size_t)b * n + node) * GD + d0);
    *(ushort8*)(dst + ((size_t)node << 11) + b * 128 + d0) = pack8(s[0], s[1]);
}

// ---------- spmm (bf16 (N,B,D) source), unroll-4 edge pipeline ----------

__global__ __launch_bounds__(256) void k_spmm(const u16* __restrict__ srcT,
                                              const int* __restrict__ off,
                                              const int* __restrict__ lst,
                                              u16* __restrict__ dstF, int ndst){
    const int node = blockIdx.x, t = threadIdx.x;
    const int b = t >> 4, d0 = (t & 15) * 8;
    float a0[8], a1[8], a2[8], a3[8];
    #pragma unroll
    for (int i = 0; i < 8; ++i){ a0[i] = 0.f; a1[i] = 0.f; a2[i] = 0.f; a3[i] = 0.f; }
    const int s = off[node], e = off[node + 1];
    const u16* base = srcT + t * 8;
    int a = s;
    for (; a + 4 <= e; a += 4){
        ushort8 v0 = *(const ushort8*)(base + ((size_t)lst[a    ] << 11));
        ushort8 v1 = *(const ushort8*)(base + ((size_t)lst[a + 1] << 11));
        ushort8 v2 = *(const ushort8*)(base + ((size_t)lst[a + 2] << 11));
        ushort8 v3 = *(const ushort8*)(base + ((size_t)lst[a + 3] << 11));
        #pragma unroll
        for (int i = 0; i < 8; ++i){
            a0[i] += bf2f(v0[i]); a1[i] += bf2f(v1[i]);
            a2[i] += bf2f(v2[i]); a3[i] += bf2f(v3[i]);
        }
    }
    for (; a < e; ++a){
        ushort8 v = *(const ushort8*)(base + ((size_t)lst[a] << 11));
        #pragma unroll
        for (int i = 0; i < 8; ++i) a0[i] += bf2f(v[i]);
    }
    float acc[8];
    #pragma unroll
    for (int i = 0; i < 8; ++i) acc[i] = (a0[i] + a1[i]) + (a2[i] + a3[i]);
    u64* p = (u64*)(dstF + fidx(b * ndst + node, d0));
    p[0] = pack4(acc[0], acc[1], acc[2], acc[3]);
    p[1] = pack4(acc[4], acc[5], acc[6], acc[7]);
}

// ---------- fused msg net: group-granular pipeline, frag I/O ----------

__global__ __launch_bounds__(512) void k_msg(u16* __restrict__ X,
                                             const u16* __restrict__ W1, const float* __restrict__ b1,
                                             const u16* __restrict__ W2, const float* __restrict__ b2,
                                             int ngroups){
    __shared__ __align__(16) u16 Gs[2][16 * 128];   // 2 x 4KB
    const int tid = threadIdx.x, lane = tid & 63, w = tid >> 6;
    const int l15 = lane & 15, rg = lane >> 4;
    const int j = w * 16 + l15;

    short8 w1f[4], w2f[4];
    #pragma unroll
    for (int ks = 0; ks < 4; ++ks){
        w1f[ks] = *(const short8*)(W1 + (size_t)j * 128 + ks * 32 + rg * 8);
        w2f[ks] = *(const short8*)(W2 + (size_t)j * 128 + ks * 32 + rg * 8);
    }
    const float bb1 = b1[j], bb2 = b2[j];

    const int stride = gridDim.x;
    const int ng = ngroups / stride;

    short8 xA[4], xB[4];
    auto loadx = [&](short8* xf, int g){
        const u16* xb = X + ((size_t)g << 11);
        #pragma unroll
        for (int ks = 0; ks < 4; ++ks) xf[ks] = *(const short8*)(xb + ks * 512 + lane * 8);
    };
    auto g1 = [&](const short8* xf, int buf){
        f32x4 acc = {0, 0, 0, 0};
        #pragma unroll
        for (int ks = 0; ks < 4; ++ks) acc = MFMA(xf[ks], w1f[ks], acc, 0, 0, 0);
        #pragma unroll
        for (int i = 0; i < 4; ++i){
            float v = acc[i] + bb1;
            float g = 0.5f * v * (1.f + erff(v * 0.70710678f));   // exact gelu
            *(u16*)swzp(Gs[buf], rg * 4 + i, j * 2) = f2bf(g);
        }
    };
    auto g2 = [&](int buf, int g){
        f32x4 acc = {0, 0, 0, 0};
        #pragma unroll
        for (int ks = 0; ks < 4; ++ks)
            acc = MFMA(ldfrag(Gs[buf], l15, lane, ks), w2f[ks], acc, 0, 0, 0);
        #pragma unroll
        for (int i = 0; i < 4; ++i)
            X[fidx(g * 16 + rg * 4 + i, j)] = f2bf(acc[i] + bb2);
    };

    int g = blockIdx.x;
    loadx(xA, g);
    g1(xA, 0);
    for (int k = 0; k < ng; k += 2){
        loadx(xB, g + stride);
        __syncthreads();
        g2(0, g);
        g1(xB, 1);
        if (k + 2 < ng) loadx(xA, g + 2 * stride);
        __syncthreads();
        g2(1, g + stride);
        if (k + 2 < ng) g1(xA, 0);
        g += 2 * stride;
    }
}

// ---------- fused GRU cell (R6 config: zero LDS, zero barriers, no SB0) ----------

__global__ __launch_bounds__(512) void k_gru(const u16* __restrict__ XF, const u16* __restrict__ HF,
                                             const u16* __restrict__ Wih, const float* __restrict__ bih,
                                             const u16* __restrict__ Whh, const float* __restrict__ bhh,
                                             float* __restrict__ Out, int ngroups){
    const int tid = threadIdx.x, lane = tid & 63, w = tid >> 6;
    const int l15 = lane & 15, rg = lane >> 4;
    const int j = w * 16 + l15;            // this lane's output column, fixed

    // register weights: wf[gate 0..2 = ih r/z/n, 3..5 = hh r/z/n][ks]
    short8 wf[6][4];
    #pragma unroll
    for (int g = 0; g < 3; ++g){
        #pragma unroll
        for (int ks = 0; ks < 4; ++ks){
            wf[g][ks]     = *(const short8*)(Wih + (size_t)(g * 128 + j) * 128 + ks * 32 + rg * 8);
            wf[g + 3][ks] = *(const short8*)(Whh + (size_t)(g * 128 + j) * 128 + ks * 32 + rg * 8);
        }
    }
    const float bir = bih[j]       + bhh[j];
    const float biz = bih[128 + j] + bhh[128 + j];
    const float bin = bih[256 + j];
    const float bhn = bhh[256 + j];

    // per-lane h0 offset within a group's 2048-u16 block
    const int h0off = ((j >> 5) << 9) + (((j & 31) >> 3) << 7) + ((rg * 4) << 3) + (j & 7);

    const int stride = gridDim.x;
    const int ng = ngroups / stride;       // 16 (v) or 8 (c), even

    short8 xfA[4], hfA[4], xfB[4], hfB[4];
    float h0A[4], h0B[4];

    auto load = [&](short8* xf, short8* hf, float* h0, int g){
        const u16* xb = XF + ((size_t)g << 11);
        const u16* hb = HF + ((size_t)g << 11);
        #pragma unroll
        for (int ks = 0; ks < 4; ++ks){
            xf[ks] = *(const short8*)(xb + ks * 512 + lane * 8);
            hf[ks] = *(const short8*)(hb + ks * 512 + lane * 8);
        }
        #pragma unroll
        for (int i = 0; i < 4; ++i) h0[i] = bf2f(hb[h0off + i * 8]);
    };

    auto comp = [&](const short8* xf, const short8* hf, const float* h0, int g){
        f32x4 ar = {0,0,0,0}, az = {0,0,0,0}, an = {0,0,0,0}, hn = {0,0,0,0};
        #pragma unroll
        for (int ks = 0; ks < 4; ++ks){
            ar = MFMA(xf[ks], wf[0][ks], ar, 0, 0, 0);
            az = MFMA(xf[ks], wf[1][ks], az, 0, 0, 0);
            an = MFMA(xf[ks], wf[2][ks], an, 0, 0, 0);
            ar = MFMA(hf[ks], wf[3][ks], ar, 0, 0, 0);
            az = MFMA(hf[ks], wf[4][ks], az, 0, 0, 0);
            hn = MFMA(hf[ks], wf[5][ks], hn, 0, 0, 0);
        }
        #pragma unroll
        for (int i = 0; i < 4; ++i){
            int r = g * 16 + rg * 4 + i;
            float rr = sigmoidf_(ar[i] + bir);
            float zz = sigmoidf_(az[i] + biz);
            float nn = tanhf_fast(an[i] + bin + rr * (hn[i] + bhn));
            Out[(size_t)r * GD + j] = (1.f - zz) * nn + zz * h0[i];
        }
    };

    int g = blockIdx.x;
    load(xfA, hfA, h0A, g);
    for (int k = 0; k < ng; k += 2){
        load(xfB, hfB, h0B, g + stride);
        comp(xfA, hfA, h0A, g);
        if (k + 2 < ng) load(xfA, hfA, h0A, g + 2 * stride);
        comp(xfB, hfB, h0B, g + stride);
        g += 2 * stride;
    }
}

// ---------- launch ----------

extern "C" void kernel_launch(void* const* d_in, const int* in_sizes, int n_in,
                              void* d_out, int out_size, void* d_ws, size_t ws_size,
                              hipStream_t stream){
    const float* v_feats  = (const float*)d_in[0];
    const float* c_feats  = (const float*)d_in[1];
    const int*   edge_chk = (const int*)d_in[2];
    const int*   edge_var = (const int*)d_in[3];
    const float* msg_w1   = (const float*)d_in[4];
    const float* msg_b1   = (const float*)d_in[5];
    const float* msg_w2   = (const float*)d_in[6];
    const float* msg_b2   = (const float*)d_in[7];
    const float* var_w_ih = (const float*)d_in[8];
    const float* var_w_hh = (const float*)d_in[9];
    const float* var_b_ih = (const float*)d_in[10];
    const float* var_b_hh = (const float*)d_in[11];
    const float* chk_w_ih = (const float*)d_in[12];
    const float* chk_w_hh = (const float*)d_in[13];
    const float* chk_b_ih = (const float*)d_in[14];
    const float* chk_b_hh = (const float*)d_in[15];

    float* out_v = (float*)d_out;
    float* out_c = out_v + (size_t)GB * GNV * GD;

    char* p = (char*)d_ws;
    auto take = [&](size_t bytes) -> void* {
        void* r = (void*)p; p += (bytes + 255) & ~(size_t)255; return r;
    };
    int* cnt_c = (int*)take(GNC * 4);
    int* cnt_v = (int*)take(GNV * 4);
    int* off_c = (int*)take((GNC + 1) * 4);
    int* off_v = (int*)take((GNV + 1) * 4);
    int* cur_c = (int*)take(GNC * 4);
    int* cur_v = (int*)take(GNV * 4);
    int* lst_c = (int*)take(GE * 4);
    int* lst_v = (int*)take(GE * 4);
    u16* w1b  = (u16*)take((size_t)GD * GD * 2);       // contiguous bf16 weights
    u16* w2b  = (u16*)take((size_t)GD * GD * 2);
    u16* cihb = (u16*)take((size_t)3 * GD * GD * 2);
    u16* chhb = (u16*)take((size_t)3 * GD * GD * 2);
    u16* vihb = (u16*)take((size_t)3 * GD * GD * 2);
    u16* vhhb = (u16*)take((size_t)3 * GD * GD * 2);
    u16* mc = (u16*)take((size_t)GB * GNC * GD * 2);   // frag-order msg buf (c side)
    u16* mv = (u16*)take((size_t)GB * GNV * GD * 2);   // frag-order msg buf (v side)
    u16* vT = (u16*)take((size_t)GNV * GB * GD * 2);   // (NV,B,D) bf16 v_feats
    u16* cT = (u16*)take((size_t)GNC * GB * GD * 2);   // (NC,B,D) bf16 c_new
    u16* vF = (u16*)take((size_t)GB * GNV * GD * 2);   // frag v_feats (GRU H)
    u16* cF = (u16*)take((size_t)GB * GNC * GD * 2);   // frag c_feats (GRU H)

    hipMemsetAsync(cnt_c, 0, (GNC + GNV) * 4, stream);
    k_hist<<<(GE + 255) / 256, 256, 0, stream>>>(edge_chk, edge_var, cnt_c, cnt_v);
    k_scan2<<<2, 1024, 0, stream>>>(cnt_c, off_c, cur_c, cnt_v, off_v, cur_v);
    k_fill<<<(GE + 255) / 256, 256, 0, stream>>>(edge_chk, edge_var, cur_c, lst_c, cur_v, lst_v);
    k_sort2<<<(GNC + GNV + 255) / 256, 256, 0, stream>>>(off_c, lst_c, off_v, lst_v);
    k_cvt6<<<896, 256, 0, stream>>>(msg_w1, msg_w2, chk_w_ih, chk_w_hh, var_w_ih, var_w_hh, w1b);
    k_trg<<<8192 + 4096, 256, 0, stream>>>(v_feats, c_feats, vT, vF, cF);

    // v -> c
    k_spmm<<<GNC, 256, 0, stream>>>(vT, off_c, lst_c, mc, GNC);
    k_msg<<<512, 512, 0, stream>>>(mc, w1b, msg_b1, w2b, msg_b2, (GB * GNC) / 16);
    k_gru<<<512, 512, 0, stream>>>(mc, cF, cihb, chk_b_ih, chhb, chk_b_hh,
                                   out_c, (GB * GNC) / 16);
    // c -> v
    k_tr1<<<GNC, 256, 0, stream>>>(out_c, cT, GNC);
    k_spmm<<<GNV, 256, 0, stream>>>(cT, off_v, lst_v, mv, GNV);
    k_msg<<<512, 512, 0, stream>>>(mv, w1b, msg_b1, w2b, msg_b2, (GB * GNV) / 16);
    k_gru<<<512, 512, 0, stream>>>(mv, vF, vihb, var_b_ih, vhhb, var_b_hh,
                                   out_v, (GB * GNV) / 16);
}